// Round 2
// baseline (2051.068 us; speedup 1.0000x reference)
//
#include <hip/hip_runtime.h>

#define NPTS 8192
#define SPTS 2048
#define KS 32
#define CF 64
#define BQ 4
#define FPS_T 512
#define PPT (NPTS / FPS_T)   // 16 points per thread
#define PPT2 (PPT / 2)       // 8 point-pairs per thread
#define FPS_SHIFT 9          // log2(FPS_T)

#define OFF_GROUPED 24576                    // B*S*3
#define GROUPED_SZ  17563648                 // B*67*S*K
#define OFF_FPSIDX  (OFF_GROUPED + GROUPED_SZ)

typedef __attribute__((ext_vector_type(2))) float vf2;
typedef unsigned long long u64;

// One u64-max DPP step: move both halves, compare-select. bound_ctrl=true ->
// OOB lanes contribute 0, which never wins (pk >= 0 always, equal-0 is a no-op).
#define DPPSTEP64(pk, ctrl) do {                                                  \
    const unsigned _lo = (unsigned)(pk), _hi = (unsigned)((pk) >> 32);            \
    const unsigned _olo =                                                         \
        (unsigned)__builtin_amdgcn_mov_dpp((int)_lo, (ctrl), 0xf, 0xf, true);     \
    const unsigned _ohi =                                                         \
        (unsigned)__builtin_amdgcn_mov_dpp((int)_hi, (ctrl), 0xf, 0xf, true);     \
    const u64 _o = ((u64)_ohi << 32) | _olo;                                      \
    (pk) = (_o > (pk)) ? _o : (pk);                                               \
} while (0)

// ---------------- FPS: one block per batch, 1 barrier per iteration ----------------
// Loop body has ZERO global-memory ops -> the waitcnt before s_barrier is free.
__global__ __launch_bounds__(FPS_T)
void fps_kernel(const float* __restrict__ xyz, float* __restrict__ out)
{
#pragma clang fp contract(off)
    __shared__ float sx[NPTS], sy[NPTS], sz[NPTS];   // 96 KiB coord planes
    __shared__ float4 rres[SPTS];                     // 32 KiB per-iter results
    __shared__ __align__(16) u64 slots[2][8];         // parity double-buffer
    const int b    = blockIdx.x;
    const int tid  = threadIdx.x;
    const int wv   = tid >> 6;
    const int lane = tid & 63;
    const float* xb = xyz + (size_t)b * (NPTS * 3);

    // SoA pair registers: component k of pair j covers points tid+512*(2j+k)
    vf2 PX[PPT2], PY[PPT2], PZ[PPT2], MD[PPT2];
#pragma unroll
    for (int j = 0; j < PPT2; ++j) {
        const int p0 = tid + FPS_T * (2 * j);
        const int p1 = p0 + FPS_T;
        const float x0 = xb[p0 * 3 + 0], y0 = xb[p0 * 3 + 1], z0 = xb[p0 * 3 + 2];
        const float x1 = xb[p1 * 3 + 0], y1 = xb[p1 * 3 + 1], z1 = xb[p1 * 3 + 2];
        sx[p0] = x0; sy[p0] = y0; sz[p0] = z0;
        sx[p1] = x1; sy[p1] = y1; sz[p1] = z1;
        vf2 vx; vx.x = x0; vx.y = x1; PX[j] = vx;
        vf2 vy; vy.x = y0; vy.y = y1; PY[j] = vy;
        vf2 vz; vz.x = z0; vz.y = z1; PZ[j] = vz;
        vf2 vm; vm.x = 1e10f; vm.y = 1e10f; MD[j] = vm;
    }

    // iteration 0: center = point 0; result buffered in LDS, written at end
    float qx = xb[0], qy = xb[1], qz = xb[2];
    if (tid == 0) {
        float4 r; r.x = qx; r.y = qy; r.z = qz; r.w = 0.0f;
        rres[0] = r;
    }

    for (int i = 1; i < SPTS; ++i) {
        vf2 qxx; qxx.x = qx; qxx.y = qx;
        vf2 qyy; qyy.x = qy; qyy.y = qy;
        vf2 qzz; qzz.x = qz; qzz.y = qz;

        // min-dist update, packed pairs; exact numpy order (dx*dx+dy*dy)+dz*dz, no fma
#pragma unroll
        for (int j = 0; j < PPT2; ++j) {
            const vf2 dx = PX[j] - qxx;
            const vf2 dy = PY[j] - qyy;
            const vf2 dz = PZ[j] - qzz;
            const vf2 d  = (dx * dx + dy * dy) + dz * dz;
            MD[j] = __builtin_elementwise_min(MD[j], d);
        }

        // packed max tree over 8 pairs, then horizontal
        vf2 m0 = __builtin_elementwise_max(MD[0], MD[1]);
        vf2 m1 = __builtin_elementwise_max(MD[2], MD[3]);
        vf2 m2 = __builtin_elementwise_max(MD[4], MD[5]);
        vf2 m3 = __builtin_elementwise_max(MD[6], MD[7]);
        m0 = __builtin_elementwise_max(m0, m1);
        m2 = __builtin_elementwise_max(m2, m3);
        m0 = __builtin_elementwise_max(m0, m2);
        const float best = fmaxf(m0.x, m0.y);

        // smallest owned jj with md[jj]==best: eq-bitmask + or-tree + ctz
        unsigned k0 = ((MD[0].x == best) ? 0x0001u : 0u) | ((MD[0].y == best) ? 0x0002u : 0u);
        unsigned k1 = ((MD[1].x == best) ? 0x0004u : 0u) | ((MD[1].y == best) ? 0x0008u : 0u);
        unsigned k2 = ((MD[2].x == best) ? 0x0010u : 0u) | ((MD[2].y == best) ? 0x0020u : 0u);
        unsigned k3 = ((MD[3].x == best) ? 0x0040u : 0u) | ((MD[3].y == best) ? 0x0080u : 0u);
        unsigned k4 = ((MD[4].x == best) ? 0x0100u : 0u) | ((MD[4].y == best) ? 0x0200u : 0u);
        unsigned k5 = ((MD[5].x == best) ? 0x0400u : 0u) | ((MD[5].y == best) ? 0x0800u : 0u);
        unsigned k6 = ((MD[6].x == best) ? 0x1000u : 0u) | ((MD[6].y == best) ? 0x2000u : 0u);
        unsigned k7 = ((MD[7].x == best) ? 0x4000u : 0u) | ((MD[7].y == best) ? 0x8000u : 0u);
        k0 |= k1; k2 |= k3; k4 |= k5; k6 |= k7;
        k0 |= k2; k4 |= k6;
        const int bj = __builtin_ctz(k0 | k4);
        const int bidx = tid + (bj << FPS_SHIFT);

        // pack (dist_bits, 8191-idx): u64 max == argmax dist, tie -> smaller idx
        u64 pk = ((u64)__float_as_uint(best) << 32) | (unsigned)(NPTS - 1 - bidx);

        // single-phase u64 DPP max, accumulates into lane 63 (no readlane needed)
        DPPSTEP64(pk, 0x111);  // row_shr:1
        DPPSTEP64(pk, 0x112);  // row_shr:2
        DPPSTEP64(pk, 0x114);  // row_shr:4
        DPPSTEP64(pk, 0x118);  // row_shr:8
        DPPSTEP64(pk, 0x142);  // row_bcast:15
        DPPSTEP64(pk, 0x143);  // row_bcast:31
        if (lane == 63) slots[i & 1][wv] = pk;
        __syncthreads();                      // the only barrier; no vmem to drain

        // cross-wave reduce: 4 x 16B broadcast LDS reads + u64 max tree
        const ulonglong2* sp = (const ulonglong2*)slots[i & 1];
        const ulonglong2 p0 = sp[0], p1 = sp[1], p2 = sp[2], p3 = sp[3];
        u64 a = p0.x > p0.y ? p0.x : p0.y;
        u64 c = p1.x > p1.y ? p1.x : p1.y;
        u64 d = p2.x > p2.y ? p2.x : p2.y;
        u64 e = p3.x > p3.y ? p3.x : p3.y;
        a = a > c ? a : c;
        d = d > e ? d : e;
        const u64 g = a > d ? a : d;
        const int widx = (NPTS - 1) - (int)(unsigned)(g & 0xffffffffull);

        // winner coords from LDS planes (uniform addr -> broadcast)
        qx = sx[widx]; qy = sy[widx]; qz = sz[widx];

        if (tid == 0) {
            float4 r; r.x = qx; r.y = qy; r.z = qz; r.w = (float)widx;
            rres[i] = r;                      // ds_write_b128, off critical path
        }
    }

    // bulk writeback of all per-iteration results (one time)
    __syncthreads();
    float* newxyz = out;
    float* fpsidx = out + OFF_FPSIDX;
#pragma unroll
    for (int j = 0; j < 4; ++j) {
        const int i = tid + (j << FPS_SHIFT);
        const float4 r = rres[i];
        fpsidx[(size_t)b * SPTS + i] = r.w;
        const size_t o = ((size_t)b * SPTS + i) * 3;
        newxyz[o + 0] = r.x; newxyz[o + 1] = r.y; newxyz[o + 2] = r.z;
    }
}

// ---------------- ball query + grouping: one wave per center ----------------
__global__ __launch_bounds__(256)
void ballgroup_kernel(const float* __restrict__ xyz, const float* __restrict__ feat,
                      float* out)
{
#pragma clang fp contract(off)
    __shared__ int idxl[4][KS];
    const int tid    = threadIdx.x;
    const int wv     = tid >> 6;
    const int lane   = tid & 63;
    const int center = blockIdx.x * 4 + wv;
    const int b      = center >> 11;          // / SPTS
    const int s      = center & (SPTS - 1);
    const float* xb  = xyz + (size_t)b * (NPTS * 3);
    const float* newxyz = out;                // written by fps_kernel earlier in stream
    const float cx = newxyz[(size_t)center * 3 + 0];
    const float cy = newxyz[(size_t)center * 3 + 1];
    const float cz = newxyz[(size_t)center * 3 + 2];

    if (lane == 0) idxl[wv][0] = 0;           // default when zero hits

    int cnt = 0;
    for (int nb = 0; nb < NPTS; nb += 64) {
        const int p = nb + lane;
        const float x = xb[p * 3 + 0];
        const float y = xb[p * 3 + 1];
        const float z = xb[p * 3 + 2];
        const float dx = cx - x, dy = cy - y, dz = cz - z;
        const float d2 = (dx * dx + dy * dy) + dz * dz;
        // f32 'd2 <= 0.04f' == numpy 'f32 d2 < float64(0.2*0.2)'
        const bool in = (d2 <= 0.04f);
        const unsigned long long mk = __ballot(in);
        if (in) {
            const int pos = cnt + __popcll(mk & ((1ull << lane) - 1ull));
            if (pos < KS) idxl[wv][pos] = p;
        }
        cnt += (int)__popcll(mk);
        if (cnt >= KS) break;                 // cnt is wave-uniform
    }
    const int cc = cnt < KS ? cnt : KS;

    // pad short lists with first hit (or 0), write padded list back
    int myidx = 0;
    if (lane < KS) {
        myidx = (lane < cc) ? idxl[wv][lane] : idxl[wv][0];
        idxl[wv][lane] = myidx;
    }

    float* grouped = out + OFF_GROUPED;
    const size_t chstride = (size_t)SPTS * KS;                    // 65536
    const size_t base67   = (size_t)b * 67 * chstride + (size_t)s * KS;

    // channels 0..2: recentered coords (point - center)
    if (lane < KS) {
        const float gx = xb[(size_t)myidx * 3 + 0] - cx;
        const float gy = xb[(size_t)myidx * 3 + 1] - cy;
        const float gz = xb[(size_t)myidx * 3 + 2] - cz;
        grouped[base67 + 0 * chstride + lane] = gx;
        grouped[base67 + 1 * chstride + lane] = gy;
        grouped[base67 + 2 * chstride + lane] = gz;
    }

    // channels 3..66: feature gather; lanes = (k, c-half)
    const int k    = lane & (KS - 1);
    const int half = lane >> 5;
    const int gi   = idxl[wv][k];
    const float* fb = feat + (size_t)b * CF * NPTS;
    const size_t obase = base67 + 3 * chstride + (size_t)k;
#pragma unroll 8
    for (int c0 = 0; c0 < 32; ++c0) {
        const int c = c0 * 2 + half;
        grouped[obase + (size_t)c * chstride] = fb[(size_t)c * NPTS + gi];
    }
}

extern "C" void kernel_launch(void* const* d_in, const int* in_sizes, int n_in,
                              void* d_out, int out_size, void* d_ws, size_t ws_size,
                              hipStream_t stream) {
    const float* xyz  = (const float*)d_in[0];
    const float* feat = (const float*)d_in[1];
    float* out = (float*)d_out;
    fps_kernel<<<dim3(BQ), dim3(FPS_T), 0, stream>>>(xyz, out);
    ballgroup_kernel<<<dim3((BQ * SPTS) / 4), dim3(256), 0, stream>>>(xyz, feat, out);
}